// Round 2
// baseline (178.434 us; speedup 1.0000x reference)
//
#include <hip/hip_runtime.h>

#define T_TOK 2048
#define DM    512
#define DFF   512
#define NE    16

typedef __attribute__((ext_vector_type(8))) short bf16x8;
typedef __attribute__((ext_vector_type(4))) float f32x4;
typedef __attribute__((ext_vector_type(8))) unsigned short us8;

__device__ __forceinline__ unsigned short f2bf(float f) {
  unsigned int u = __float_as_uint(f);
  u += 0x7fffu + ((u >> 16) & 1u);   // round-to-nearest-even
  return (unsigned short)(u >> 16);
}

__device__ __forceinline__ us8 pack8(float4 v0, float4 v1) {
  us8 o;
  o[0]=f2bf(v0.x); o[1]=f2bf(v0.y); o[2]=f2bf(v0.z); o[3]=f2bf(v0.w);
  o[4]=f2bf(v1.x); o[5]=f2bf(v1.y); o[6]=f2bf(v1.z); o[7]=f2bf(v1.w);
  return o;
}

// async global->LDS DMA, 16 B per lane; lds base must be wave-uniform
__device__ __forceinline__ void dma16(const unsigned short* g, unsigned short* l) {
  __builtin_amdgcn_global_load_lds(
      (const __attribute__((address_space(1))) unsigned int*)g,
      (__attribute__((address_space(3))) unsigned int*)l, 16, 0, 0);
}

// XOR-swizzled LDS tile rows of 64 bf16 (128 B/row), chunk c of row r
// stored at slot c ^ (r & 7). 2-way bank aliasing on read (free, m136).
#define LDSOFF(row, chunk) ((((row) << 7) + ((((chunk) ^ ((row) & 7))) << 4)))

#define MFMA(a,b,c) __builtin_amdgcn_mfma_f32_16x16x32_bf16((a),(b),(c),0,0,0)

// ---------------- prep: router (512 blocks) + zero out -------------------
__global__ __launch_bounds__(256) void prep_kernel(
    const float* __restrict__ x, const float* __restrict__ gw,
    const float* __restrict__ bias, int* __restrict__ counts,
    int* __restrict__ list, float* __restrict__ wgt,
    float* __restrict__ out)
{
  const int tid = threadIdx.x;
  // zero out: 262144 float4 over 512*256 threads -> 2 each
  {
    const int g = blockIdx.x * 256 + tid;
    const float4 z4 = {0.f, 0.f, 0.f, 0.f};
    ((float4*)out)[g] = z4;
    ((float4*)out)[g + 131072] = z4;
  }

  // ---- router: one token per wave ----
  __shared__ float lg[4][16];
  __shared__ int bcnt[16], bbase[16];
  __shared__ int sel_s[4][3], pos_s[4][3];
  __shared__ float g_s[4][3];

  const int w = tid >> 6, lane = tid & 63;
  if (tid < 16) bcnt[tid] = 0;
  const int tok = blockIdx.x * 4 + w;
  const int e = lane & 15, part = lane >> 4;

  const float* xr = x + (size_t)tok * DM + part * 128;
  const float* wr = gw + (size_t)e * DM + part * 128;
  float acc = 0.f;
  #pragma unroll 8
  for (int i = 0; i < 128; i += 4) {
    float4 xv = *(const float4*)(xr + i);
    float4 wv = *(const float4*)(wr + i);
    acc += xv.x*wv.x + xv.y*wv.y + xv.z*wv.z + xv.w*wv.w;
  }
  acc += __shfl_xor(acc, 16);
  acc += __shfl_xor(acc, 32);
  if (lane < 16) lg[w][lane] = 1.f / (1.f + __expf(-acc));  // affinity
  __syncthreads();

  if (tid < 4) {
    float aff[16], sc[16];
    #pragma unroll
    for (int i = 0; i < 16; ++i) { aff[i] = lg[tid][i]; sc[i] = aff[i] + bias[i]; }
    int sel[3]; float sa[3]; float sum = 0.f;
    #pragma unroll
    for (int k = 0; k < 3; ++k) {
      float best = -1e30f; int bi = 0;
      for (int i = 0; i < 16; ++i) {
        bool used = false;
        for (int j = 0; j < k; ++j) used |= (sel[j] == i);
        if (!used && sc[i] > best) { best = sc[i]; bi = i; }
      }
      sel[k] = bi; sa[k] = aff[bi]; sum += aff[bi];
    }
    float inv = 1.f / (sum + 1e-9f);
    #pragma unroll
    for (int k = 0; k < 3; ++k) {
      int p = atomicAdd(&bcnt[sel[k]], 1);
      sel_s[tid][k] = sel[k]; pos_s[tid][k] = p; g_s[tid][k] = sa[k] * inv;
    }
  }
  __syncthreads();
  if (tid < 16) bbase[tid] = atomicAdd(&counts[tid], bcnt[tid]);
  __syncthreads();
  if (tid < 4) {
    #pragma unroll
    for (int k = 0; k < 3; ++k) {
      int E = sel_s[tid][k];
      int p = bbase[E] + pos_s[tid][k];
      list[E * T_TOK + p] = blockIdx.x * 4 + tid;
      wgt [E * T_TOK + p] = g_s[tid][k];
    }
  }
}

// ---------------- GEMM1: 128x64 tiles, fp32 reg-staged + in-flight cvt ----
// Reads fp32 X/W directly (no pre-convert pass). Per K-tile: issue global
// loads early, MFMA on current buffer, cvt+ds_write late (T14).
__global__ __launch_bounds__(256, 2) void gemm1_fused(
    const float* __restrict__ X, const float* __restrict__ Wsh,
    const float* __restrict__ Wex, unsigned short* __restrict__ Hall,
    const int* __restrict__ counts, const int* __restrict__ list)
{
  __shared__ unsigned short SA[2][128][64];   // 32 KB
  __shared__ unsigned short SG[2][64][64];    // 16 KB
  __shared__ unsigned short SU[2][64][64];    // 16 KB

  const int n0 = blockIdx.x * 64;           // H col block
  const int mt = blockIdx.y, z = blockIdx.z;
  int cnt, hb; const float* W;
  if (z == 0) { cnt = T_TOK; hb = 0; W = Wsh; }
  else {
    const int e = z - 1;
    cnt = counts[e];
    if (mt * 128 >= cnt) return;
    hb = T_TOK;
    for (int i = 0; i < e; ++i) hb += counts[i];
    W = Wex + (size_t)e * (2 * DFF * DM);
  }

  const int tid = threadIdx.x, w = tid >> 6, lane = tid & 63;
  const int rsub = lane >> 3;                // row within 8-row stripe
  const int c    = lane & 7;                 // 8-float chunk in K-window

  const float* gA[4];
  unsigned short* lA[2][4];
  #pragma unroll
  for (int q = 0; q < 4; ++q) {
    const int rA = q * 32 + w * 8 + rsub;    // local row 0..127
    int ra = mt * 128 + rA;
    int rc = ra < cnt ? ra : cnt - 1;
    int tokr = (z == 0) ? rc : list[(z - 1) * T_TOK + rc];
    gA[q] = X + (size_t)tokr * DM + c * 8;
    #pragma unroll
    for (int b = 0; b < 2; ++b)
      lA[b][q] = &SA[b][rA][0] + ((c ^ (rA & 7)) << 3);
  }
  const float *gG[2], *gU[2];
  unsigned short *lG[2][2], *lU[2][2];
  #pragma unroll
  for (int q = 0; q < 2; ++q) {
    const int rB = q * 32 + w * 8 + rsub;    // local row 0..63
    const int rb = n0 + rB;
    gG[q] = W + (size_t)rb * DM + c * 8;
    gU[q] = W + (size_t)(DFF + rb) * DM + c * 8;
    #pragma unroll
    for (int b = 0; b < 2; ++b) {
      lG[b][q] = &SG[b][rB][0] + ((c ^ (rB & 7)) << 3);
      lU[b][q] = &SU[b][rB][0] + ((c ^ (rB & 7)) << 3);
    }
  }

  const int wm = (w & 1) * 64;               // wave row base (0 / 64)
  const int wn = (w >> 1) * 32;              // wave col base (0 / 32)
  const int lr = lane & 15, qd = lane >> 4;
  const char* const sa = (const char*)SA;
  const char* const sg = (const char*)SG;
  const char* const su = (const char*)SU;

  const f32x4 z4 = {0.f, 0.f, 0.f, 0.f};
  f32x4 accg[4][2], accu[4][2];
  #pragma unroll
  for (int i = 0; i < 4; ++i)
    #pragma unroll
    for (int j = 0; j < 2; ++j) { accg[i][j] = z4; accu[i][j] = z4; }

  float4 av0[4], av1[4], gv0[2], gv1[2], uv0[2], uv1[2];

  // prologue: stage tile 0 into buf 0
  #pragma unroll
  for (int q = 0; q < 4; ++q) {
    av0[q] = *(const float4*)gA[q]; av1[q] = *(const float4*)(gA[q] + 4);
  }
  #pragma unroll
  for (int q = 0; q < 2; ++q) {
    gv0[q] = *(const float4*)gG[q]; gv1[q] = *(const float4*)(gG[q] + 4);
    uv0[q] = *(const float4*)gU[q]; uv1[q] = *(const float4*)(gU[q] + 4);
  }
  #pragma unroll
  for (int q = 0; q < 4; ++q) *(us8*)lA[0][q] = pack8(av0[q], av1[q]);
  #pragma unroll
  for (int q = 0; q < 2; ++q) {
    *(us8*)lG[0][q] = pack8(gv0[q], gv1[q]);
    *(us8*)lU[0][q] = pack8(uv0[q], uv1[q]);
  }

  #pragma unroll
  for (int i = 0; i < DM / 64; ++i) {
    const int b = i & 1;
    __syncthreads();                         // buf b ready
    if (i + 1 < DM / 64) {                   // issue next-tile loads early
      const int k1 = (i + 1) * 64;
      #pragma unroll
      for (int q = 0; q < 4; ++q) {
        av0[q] = *(const float4*)(gA[q] + k1);
        av1[q] = *(const float4*)(gA[q] + k1 + 4);
      }
      #pragma unroll
      for (int q = 0; q < 2; ++q) {
        gv0[q] = *(const float4*)(gG[q] + k1);
        gv1[q] = *(const float4*)(gG[q] + k1 + 4);
        uv0[q] = *(const float4*)(gU[q] + k1);
        uv1[q] = *(const float4*)(gU[q] + k1 + 4);
      }
    }
    const int boA = b * 16384;               // A buffer byte offset (128*64*2)
    const int boB = b * 8192;                // G/U buffer byte offset
    #pragma unroll
    for (int ks = 0; ks < 2; ++ks) {
      const int ch = ks * 4 + qd;            // 16B chunk index in row
      bf16x8 a[4], g[2], u[2];
      #pragma unroll
      for (int sm = 0; sm < 4; ++sm)
        a[sm] = *(const bf16x8*)(sa + boA + LDSOFF(wm + sm * 16 + lr, ch));
      #pragma unroll
      for (int sn = 0; sn < 2; ++sn) {
        g[sn] = *(const bf16x8*)(sg + boB + LDSOFF(wn + sn * 16 + lr, ch));
        u[sn] = *(const bf16x8*)(su + boB + LDSOFF(wn + sn * 16 + lr, ch));
      }
      #pragma unroll
      for (int sm = 0; sm < 4; ++sm)
        #pragma unroll
        for (int sn = 0; sn < 2; ++sn) {
          accg[sm][sn] = MFMA(a[sm], g[sn], accg[sm][sn]);
          accu[sm][sn] = MFMA(a[sm], u[sn], accu[sm][sn]);
        }
    }
    if (i + 1 < DM / 64) {                   // cvt + write next buffer late
      const int nb = b ^ 1;
      #pragma unroll
      for (int q = 0; q < 4; ++q) *(us8*)lA[nb][q] = pack8(av0[q], av1[q]);
      #pragma unroll
      for (int q = 0; q < 2; ++q) {
        *(us8*)lG[nb][q] = pack8(gv0[q], gv1[q]);
        *(us8*)lU[nb][q] = pack8(uv0[q], uv1[q]);
      }
    }
  }

  #pragma unroll
  for (int sm = 0; sm < 4; ++sm)
    #pragma unroll
    for (int sn = 0; sn < 2; ++sn) {
      const int col = n0 + wn + sn * 16 + lr;
      #pragma unroll
      for (int r = 0; r < 4; ++r) {
        const int ent = mt * 128 + wm + sm * 16 + qd * 4 + r;
        if (ent < cnt) {
          float g = accg[sm][sn][r];
          float u = accu[sm][sn][r];
          float h = (g / (1.f + __expf(-g))) * u;   // silu(g)*u
          Hall[(size_t)(hb + ent) * DFF + col] = f2bf(h);
        }
      }
    }
}

// ---------------- GEMM2: A via DMA (Hall bf16), B fp32 reg-staged ---------
__global__ __launch_bounds__(256, 3) void gemm2_fused(
    const unsigned short* __restrict__ Hall, const float* __restrict__ Wsh,
    const float* __restrict__ Wex, float* __restrict__ out,
    const int* __restrict__ counts, const int* __restrict__ list,
    const float* __restrict__ wgt)
{
  __shared__ unsigned short SA[2][128][64];   // 32 KB
  __shared__ unsigned short SB[2][64][64];    // 16 KB

  const int n0 = blockIdx.x * 64;           // out col block
  const int mt = blockIdx.y, z = blockIdx.z;
  int cnt, hb; const float* W;
  if (z == 0) { cnt = T_TOK; hb = 0; W = Wsh; }
  else {
    const int e = z - 1;
    cnt = counts[e];
    if (mt * 128 >= cnt) return;
    hb = T_TOK;
    for (int i = 0; i < e; ++i) hb += counts[i];
    W = Wex + (size_t)e * (DM * DFF);
  }

  const int tid = threadIdx.x, w = tid >> 6, lane = tid & 63;
  const int rsub = lane >> 3;
  const int c    = lane & 7;
  const int cch  = c ^ rsub;                 // pre-swizzled source chunk (DMA)

  // A: Hall (bf16) via global_load_lds, linear dest + pre-swizzled source
  const unsigned short* ga[4];
  unsigned short* lA[2][4];
  #pragma unroll
  for (int q = 0; q < 4; ++q) {
    int ra = mt * 128 + q * 32 + w * 8 + rsub;
    int rc = ra < cnt ? ra : cnt - 1;
    ga[q] = Hall + (size_t)(hb + rc) * DFF + cch * 8;
    #pragma unroll
    for (int b = 0; b < 2; ++b)
      lA[b][q] = &SA[b][q * 32 + w * 8][0];
  }
  // B: fp32 weights, reg-staged + cvt
  const float* gB[2];
  unsigned short* lB[2][2];
  #pragma unroll
  for (int q = 0; q < 2; ++q) {
    const int rB = q * 32 + w * 8 + rsub;
    gB[q] = W + (size_t)(n0 + rB) * DFF + c * 8;
    #pragma unroll
    for (int b = 0; b < 2; ++b)
      lB[b][q] = &SB[b][rB][0] + ((c ^ (rB & 7)) << 3);
  }

  const int wm = (w & 1) * 64;
  const int wn = (w >> 1) * 32;
  const int lr = lane & 15, qd = lane >> 4;
  const char* const sa = (const char*)SA;
  const char* const sb = (const char*)SB;

  const f32x4 z4 = {0.f, 0.f, 0.f, 0.f};
  f32x4 acc[4][2];
  #pragma unroll
  for (int i = 0; i < 4; ++i)
    #pragma unroll
    for (int j = 0; j < 2; ++j) acc[i][j] = z4;

  float4 bv0[2], bv1[2];

  // prologue
  #pragma unroll
  for (int q = 0; q < 4; ++q) dma16(ga[q], lA[0][q]);
  #pragma unroll
  for (int q = 0; q < 2; ++q) {
    bv0[q] = *(const float4*)gB[q]; bv1[q] = *(const float4*)(gB[q] + 4);
  }
  #pragma unroll
  for (int q = 0; q < 2; ++q) *(us8*)lB[0][q] = pack8(bv0[q], bv1[q]);

  #pragma unroll
  for (int i = 0; i < DFF / 64; ++i) {
    const int b = i & 1;
    __syncthreads();
    if (i + 1 < DFF / 64) {
      const int k1 = (i + 1) * 64, nb = b ^ 1;
      #pragma unroll
      for (int q = 0; q < 4; ++q) dma16(ga[q] + k1, lA[nb][q]);
      #pragma unroll
      for (int q = 0; q < 2; ++q) {
        bv0[q] = *(const float4*)(gB[q] + k1);
        bv1[q] = *(const float4*)(gB[q] + k1 + 4);
      }
    }
    const int boA = b * 16384;
    const int boB = b * 8192;
    #pragma unroll
    for (int ks = 0; ks < 2; ++ks) {
      const int ch = ks * 4 + qd;
      bf16x8 a[4], bb[2];
      #pragma unroll
      for (int sm = 0; sm < 4; ++sm)
        a[sm] = *(const bf16x8*)(sa + boA + LDSOFF(wm + sm * 16 + lr, ch));
      #pragma unroll
      for (int sn = 0; sn < 2; ++sn)
        bb[sn] = *(const bf16x8*)(sb + boB + LDSOFF(wn + sn * 16 + lr, ch));
      #pragma unroll
      for (int sm = 0; sm < 4; ++sm)
        #pragma unroll
        for (int sn = 0; sn < 2; ++sn)
          acc[sm][sn] = MFMA(a[sm], bb[sn], acc[sm][sn]);
    }
    if (i + 1 < DFF / 64) {
      const int nb = b ^ 1;
      #pragma unroll
      for (int q = 0; q < 2; ++q) *(us8*)lB[nb][q] = pack8(bv0[q], bv1[q]);
    }
  }

  #pragma unroll
  for (int sm = 0; sm < 4; ++sm)
    #pragma unroll
    for (int sn = 0; sn < 2; ++sn) {
      const int col = n0 + wn + sn * 16 + lr;
      #pragma unroll
      for (int r = 0; r < 4; ++r) {
        const int ent = mt * 128 + wm + sm * 16 + qd * 4 + r;
        if (ent < cnt) {
          float v = acc[sm][sn][r];
          if (z == 0) {
            atomicAdd(out + (size_t)ent * DM + col, v);
          } else {
            const int   tok = list[(z - 1) * T_TOK + ent];
            const float g   = wgt [(z - 1) * T_TOK + ent];
            atomicAdd(out + (size_t)tok * DM + col, g * v);
          }
        }
      }
    }
}

// ---------------------------------------------------------------------------
extern "C" void kernel_launch(void* const* d_in, const int* in_sizes, int n_in,
                              void* d_out, int out_size, void* d_ws, size_t ws_size,
                              hipStream_t stream) {
  const float* x    = (const float*)d_in[0];
  const float* gw   = (const float*)d_in[1];
  const float* bias = (const float*)d_in[2];
  const float* sgu  = (const float*)d_in[3];
  const float* sdn  = (const float*)d_in[4];
  const float* egu  = (const float*)d_in[5];
  const float* edn  = (const float*)d_in[6];
  float* out = (float*)d_out;

  // workspace layout (bytes)
  char* ws = (char*)d_ws;
  int*            counts = (int*)(ws + 0);        // 16 ints
  int*            list   = (int*)(ws + 64);       // 16*2048 ints
  float*          wgt    = (float*)(ws + 131136); // 16*2048 floats
  unsigned short* Hall   = (unsigned short*)(ws + 262208); // 8192*512 bf16
  const size_t need = 8650816;
  if (ws_size < need) return;

  hipMemsetAsync(counts, 0, 64, stream);
  prep_kernel<<<512, 256, 0, stream>>>(x, gw, bias, counts, list, wgt, out);
  gemm1_fused<<<dim3(8, 16, NE + 1), 256, 0, stream>>>(x, sgu, egu, Hall, counts, list);
  gemm2_fused<<<dim3(8, 16, NE + 1), 256, 0, stream>>>(Hall, sdn, edn, out, counts, list, wgt);
}

// Round 3
// 173.569 us; speedup vs baseline: 1.0280x; 1.0280x over previous
//
#include <hip/hip_runtime.h>

#define T_TOK 2048
#define DM    512
#define DFF   512
#define NE    16

typedef __attribute__((ext_vector_type(8))) short bf16x8;
typedef __attribute__((ext_vector_type(4))) float f32x4;
typedef __attribute__((ext_vector_type(8))) unsigned short us8;

__device__ __forceinline__ unsigned short f2bf(float f) {
  unsigned int u = __float_as_uint(f);
  u += 0x7fffu + ((u >> 16) & 1u);   // round-to-nearest-even
  return (unsigned short)(u >> 16);
}

// async global->LDS DMA, 16 B per lane; lds base must be wave-uniform
__device__ __forceinline__ void dma16(const unsigned short* g, unsigned short* l) {
  __builtin_amdgcn_global_load_lds(
      (const __attribute__((address_space(1))) unsigned int*)g,
      (__attribute__((address_space(3))) unsigned int*)l, 16, 0, 0);
}

// XOR-swizzled LDS tile: 64 rows x 64 bf16 (128 B/row), chunk c of row r
// stored at slot c ^ (r & 7). DMA windows (1024 B) stay contiguous; readers
// get 2-way bank aliasing (free, m136).
#define LDSOFF(row, chunk) ((((row) << 7) + ((((chunk) ^ ((row) & 7))) << 4)))

#define MFMA(a,b,c) __builtin_amdgcn_mfma_f32_16x16x32_bf16((a),(b),(c),0,0,0)

// ---------------- prep: blocks 0..511 router, 512+ convert + zero out ------
__global__ __launch_bounds__(256) void prep_kernel(
    const float* __restrict__ x, const float* __restrict__ gw,
    const float* __restrict__ bias, int* __restrict__ counts,
    int* __restrict__ list, float* __restrict__ wgt,
    const float* __restrict__ sgu, const float* __restrict__ sdn,
    const float* __restrict__ egu, const float* __restrict__ edn,
    unsigned short* __restrict__ xb,   unsigned short* __restrict__ sgub,
    unsigned short* __restrict__ sdnb, unsigned short* __restrict__ egub,
    unsigned short* __restrict__ ednb, float* __restrict__ out)
{
  const int tid = threadIdx.x;
  if (blockIdx.x >= 512) {
    // zero out (2048*512 fp32 = 262144 float4) + convert fp32->bf16
    const int cb = blockIdx.x - 512;           // 0..7039
    const int ct = cb * 256 + tid;
    const int CT = 7040 * 256;
    const float4 z4 = {0.f, 0.f, 0.f, 0.f};
    for (int i = ct; i < 262144; i += CT) ((float4*)out)[i] = z4;
    // groups of 8: x 131072 | sgu 65536 | sdn 32768 | egu 1048576 | edn 524288
    int g = ct;
    const float* s; unsigned short* d; int l;
    if      (g <  131072) { s = x;   d = xb;   l = g;           }
    else if (g <  196608) { s = sgu; d = sgub; l = g -  131072; }
    else if (g <  229376) { s = sdn; d = sdnb; l = g -  196608; }
    else if (g < 1277952) { s = egu; d = egub; l = g -  229376; }
    else                  { s = edn; d = ednb; l = g - 1277952; }
    const float* p = s + (size_t)l * 8;
    float4 v0 = *(const float4*)p;
    float4 v1 = *(const float4*)(p + 4);
    us8 o;
    o[0]=f2bf(v0.x); o[1]=f2bf(v0.y); o[2]=f2bf(v0.z); o[3]=f2bf(v0.w);
    o[4]=f2bf(v1.x); o[5]=f2bf(v1.y); o[6]=f2bf(v1.z); o[7]=f2bf(v1.w);
    *(us8*)(d + (size_t)l * 8) = o;
    return;
  }

  // ---- router: one token per wave ----
  __shared__ float lg[4][16];
  __shared__ int bcnt[16], bbase[16];
  __shared__ int sel_s[4][3], pos_s[4][3];
  __shared__ float g_s[4][3];

  const int w = tid >> 6, lane = tid & 63;
  if (tid < 16) bcnt[tid] = 0;
  const int tok = blockIdx.x * 4 + w;
  const int e = lane & 15, part = lane >> 4;

  const float* xr = x + (size_t)tok * DM + part * 128;
  const float* wr = gw + (size_t)e * DM + part * 128;
  float acc = 0.f;
  #pragma unroll 8
  for (int i = 0; i < 128; i += 4) {
    float4 xv = *(const float4*)(xr + i);
    float4 wv = *(const float4*)(wr + i);
    acc += xv.x*wv.x + xv.y*wv.y + xv.z*wv.z + xv.w*wv.w;
  }
  acc += __shfl_xor(acc, 16);
  acc += __shfl_xor(acc, 32);
  if (lane < 16) lg[w][lane] = 1.f / (1.f + __expf(-acc));  // affinity
  __syncthreads();

  if (tid < 4) {
    float aff[16], sc[16];
    #pragma unroll
    for (int i = 0; i < 16; ++i) { aff[i] = lg[tid][i]; sc[i] = aff[i] + bias[i]; }
    int sel[3]; float sa[3]; float sum = 0.f;
    #pragma unroll
    for (int k = 0; k < 3; ++k) {
      float best = -1e30f; int bi = 0;
      for (int i = 0; i < 16; ++i) {
        bool used = false;
        for (int j = 0; j < k; ++j) used |= (sel[j] == i);
        if (!used && sc[i] > best) { best = sc[i]; bi = i; }
      }
      sel[k] = bi; sa[k] = aff[bi]; sum += aff[bi];
    }
    float inv = 1.f / (sum + 1e-9f);
    #pragma unroll
    for (int k = 0; k < 3; ++k) {
      int p = atomicAdd(&bcnt[sel[k]], 1);
      sel_s[tid][k] = sel[k]; pos_s[tid][k] = p; g_s[tid][k] = sa[k] * inv;
    }
  }
  __syncthreads();
  if (tid < 16) bbase[tid] = atomicAdd(&counts[tid], bcnt[tid]);
  __syncthreads();
  if (tid < 4) {
    #pragma unroll
    for (int k = 0; k < 3; ++k) {
      int E = sel_s[tid][k];
      int p = bbase[E] + pos_s[tid][k];
      list[E * T_TOK + p] = blockIdx.x * 4 + tid;
      wgt [E * T_TOK + p] = g_s[tid][k];
    }
  }
}

// ---------------- GEMM1: 64x64 tiles, 3-deep pipeline, counted vmcnt -------
// z=0 shared expert, z>=1 routed expert z-1. Fused silu(g)*u -> Hall (bf16).
// Per tile each lane issues 6 DMAs; steady-state keeps 2 tiles (12 loads)
// in flight across raw barriers; s_waitcnt vmcnt(6) retires the oldest tile.
__global__ __launch_bounds__(256, 2) void gemm1_fused(
    const unsigned short* __restrict__ X, const unsigned short* __restrict__ Wsh,
    const unsigned short* __restrict__ Wex, unsigned short* __restrict__ Hall,
    const int* __restrict__ counts, const int* __restrict__ list)
{
  __shared__ unsigned short SA[3][64][64];   // 24 KB
  __shared__ unsigned short SG[3][64][64];   // 24 KB
  __shared__ unsigned short SU[3][64][64];   // 24 KB

  const int n0 = blockIdx.x * 64;           // H col block
  const int mt = blockIdx.y, z = blockIdx.z;
  int cnt, hb; const unsigned short* W;
  if (z == 0) { cnt = T_TOK; hb = 0; W = Wsh; }
  else {
    const int e = z - 1;
    cnt = counts[e];
    if (mt * 64 >= cnt) return;
    hb = T_TOK;
    for (int i = 0; i < e; ++i) hb += counts[i];
    W = Wex + (size_t)e * (2 * DFF * DM);
  }

  const int tid = threadIdx.x, w = tid >> 6, lane = tid & 63;
  // staging: wave w owns rows 16w..16w+15 via 2 DMA windows of 8 rows
  const int r0 = w * 16 + (lane >> 3);       // q=0 row; q=1 row = r0+8
  const int cch = (lane & 7) ^ (r0 & 7);     // src chunk (XOR swizzle)
  const unsigned short* ga[2];
  #pragma unroll
  for (int q = 0; q < 2; ++q) {
    int ra = mt * 64 + r0 + q * 8;
    int rc = ra < cnt ? ra : cnt - 1;
    int tokr = (z == 0) ? rc : list[(z - 1) * T_TOK + rc];
    ga[q] = X + (size_t)tokr * DM + cch * 8;
  }
  const unsigned short *gg[2], *gu[2];
  #pragma unroll
  for (int q = 0; q < 2; ++q) {
    int rb = n0 + r0 + q * 8;
    gg[q] = W + (size_t)rb * DM + cch * 8;
    gu[q] = W + (size_t)(DFF + rb) * DM + cch * 8;
  }
  unsigned short* lA[3][2]; unsigned short* lG[3][2]; unsigned short* lU[3][2];
  #pragma unroll
  for (int b = 0; b < 3; ++b)
    #pragma unroll
    for (int q = 0; q < 2; ++q) {
      lA[b][q] = &SA[b][w * 16 + q * 8][0];
      lG[b][q] = &SG[b][w * 16 + q * 8][0];
      lU[b][q] = &SU[b][w * 16 + q * 8][0];
    }

  const int wm = ((tid >> 6) & 1) * 32;
  const int wn = ((tid >> 7) & 1) * 32;
  const int lr = lane & 15, qd = lane >> 4;
  const char* const sa = (const char*)SA;
  const char* const sg = (const char*)SG;
  const char* const su = (const char*)SU;

  const f32x4 z4 = {0.f, 0.f, 0.f, 0.f};
  f32x4 accg[2][2], accu[2][2];
  #pragma unroll
  for (int i = 0; i < 2; ++i)
    #pragma unroll
    for (int j = 0; j < 2; ++j) { accg[i][j] = z4; accu[i][j] = z4; }

  // prologue: stage tiles 0 and 1 (order matters for vmcnt counting)
  #pragma unroll
  for (int q = 0; q < 2; ++q) {
    dma16(ga[q], lA[0][q]); dma16(gg[q], lG[0][q]); dma16(gu[q], lU[0][q]);
  }
  __builtin_amdgcn_sched_barrier(0);
  #pragma unroll
  for (int q = 0; q < 2; ++q) {
    dma16(ga[q] + 64, lA[1][q]); dma16(gg[q] + 64, lG[1][q]); dma16(gu[q] + 64, lU[1][q]);
  }

  #pragma unroll
  for (int t = 0; t < DM / 64; ++t) {
    if (t < DM / 64 - 1) asm volatile("s_waitcnt vmcnt(6)" ::: "memory");
    else                 asm volatile("s_waitcnt vmcnt(0)" ::: "memory");
    __builtin_amdgcn_sched_barrier(0);
    __builtin_amdgcn_s_barrier();           // tile t ready; t-1 fully consumed
    if (t + 2 < DM / 64) {
      const int nb = (t + 2) % 3, k2 = (t + 2) * 64;
      #pragma unroll
      for (int q = 0; q < 2; ++q) {
        dma16(ga[q] + k2, lA[nb][q]);
        dma16(gg[q] + k2, lG[nb][q]);
        dma16(gu[q] + k2, lU[nb][q]);
      }
    }
    const int bo = (t % 3) * 8192;           // buffer byte offset
    #pragma unroll
    for (int ks = 0; ks < 2; ++ks) {
      const int ch = ks * 4 + qd;            // 16B chunk index in row
      bf16x8 a0 = *(const bf16x8*)(sa + bo + LDSOFF(wm      + lr, ch));
      bf16x8 a1 = *(const bf16x8*)(sa + bo + LDSOFF(wm + 16 + lr, ch));
      bf16x8 g0 = *(const bf16x8*)(sg + bo + LDSOFF(wn      + lr, ch));
      bf16x8 g1 = *(const bf16x8*)(sg + bo + LDSOFF(wn + 16 + lr, ch));
      bf16x8 u0 = *(const bf16x8*)(su + bo + LDSOFF(wn      + lr, ch));
      bf16x8 u1 = *(const bf16x8*)(su + bo + LDSOFF(wn + 16 + lr, ch));
      __builtin_amdgcn_s_setprio(1);
      accg[0][0] = MFMA(a0, g0, accg[0][0]);
      accg[0][1] = MFMA(a0, g1, accg[0][1]);
      accg[1][0] = MFMA(a1, g0, accg[1][0]);
      accg[1][1] = MFMA(a1, g1, accg[1][1]);
      accu[0][0] = MFMA(a0, u0, accu[0][0]);
      accu[0][1] = MFMA(a0, u1, accu[0][1]);
      accu[1][0] = MFMA(a1, u0, accu[1][0]);
      accu[1][1] = MFMA(a1, u1, accu[1][1]);
      __builtin_amdgcn_s_setprio(0);
    }
  }

  #pragma unroll
  for (int sm = 0; sm < 2; ++sm)
    #pragma unroll
    for (int sn = 0; sn < 2; ++sn) {
      const int col = n0 + wn + sn * 16 + lr;
      #pragma unroll
      for (int r = 0; r < 4; ++r) {
        const int ent = mt * 64 + wm + sm * 16 + qd * 4 + r;
        if (ent < cnt) {
          float g = accg[sm][sn][r];
          float u = accu[sm][sn][r];
          float h = (g / (1.f + __expf(-g))) * u;   // silu(g)*u
          Hall[(size_t)(hb + ent) * DFF + col] = f2bf(h);
        }
      }
    }
}

// ---------------- GEMM2: 64x64 tiles, 3-deep pipeline, counted vmcnt -------
__global__ __launch_bounds__(256, 3) void gemm2_fused(
    const unsigned short* __restrict__ Hall, const unsigned short* __restrict__ Wsh,
    const unsigned short* __restrict__ Wex, float* __restrict__ out,
    const int* __restrict__ counts, const int* __restrict__ list,
    const float* __restrict__ wgt)
{
  __shared__ unsigned short SA[3][64][64];   // 24 KB
  __shared__ unsigned short SB[3][64][64];   // 24 KB

  const int n0 = blockIdx.x * 64;           // out col block
  const int mt = blockIdx.y, z = blockIdx.z;
  int cnt, hb; const unsigned short* W;
  if (z == 0) { cnt = T_TOK; hb = 0; W = Wsh; }
  else {
    const int e = z - 1;
    cnt = counts[e];
    if (mt * 64 >= cnt) return;
    hb = T_TOK;
    for (int i = 0; i < e; ++i) hb += counts[i];
    W = Wex + (size_t)e * (DM * DFF);
  }

  const int tid = threadIdx.x, w = tid >> 6, lane = tid & 63;
  const int r0 = w * 16 + (lane >> 3);
  const int cch = (lane & 7) ^ (r0 & 7);
  const unsigned short* ga[2];
  #pragma unroll
  for (int q = 0; q < 2; ++q) {
    int ra = mt * 64 + r0 + q * 8;
    int rc = ra < cnt ? ra : cnt - 1;
    ga[q] = Hall + (size_t)(hb + rc) * DFF + cch * 8;
  }
  const unsigned short* gb[2];
  #pragma unroll
  for (int q = 0; q < 2; ++q)
    gb[q] = W + (size_t)(n0 + r0 + q * 8) * DFF + cch * 8;
  unsigned short* lA[3][2]; unsigned short* lB[3][2];
  #pragma unroll
  for (int b = 0; b < 3; ++b)
    #pragma unroll
    for (int q = 0; q < 2; ++q) {
      lA[b][q] = &SA[b][w * 16 + q * 8][0];
      lB[b][q] = &SB[b][w * 16 + q * 8][0];
    }

  const int wm = ((tid >> 6) & 1) * 32;
  const int wn = ((tid >> 7) & 1) * 32;
  const int lr = lane & 15, qd = lane >> 4;
  const char* const sa = (const char*)SA;
  const char* const sb = (const char*)SB;

  const f32x4 z4 = {0.f, 0.f, 0.f, 0.f};
  f32x4 acc[2][2];
  #pragma unroll
  for (int i = 0; i < 2; ++i)
    #pragma unroll
    for (int j = 0; j < 2; ++j) acc[i][j] = z4;

  // prologue: stage tiles 0 and 1
  #pragma unroll
  for (int q = 0; q < 2; ++q) { dma16(ga[q], lA[0][q]); dma16(gb[q], lB[0][q]); }
  __builtin_amdgcn_sched_barrier(0);
  #pragma unroll
  for (int q = 0; q < 2; ++q) { dma16(ga[q] + 64, lA[1][q]); dma16(gb[q] + 64, lB[1][q]); }

  #pragma unroll
  for (int t = 0; t < DFF / 64; ++t) {
    if (t < DFF / 64 - 1) asm volatile("s_waitcnt vmcnt(4)" ::: "memory");
    else                  asm volatile("s_waitcnt vmcnt(0)" ::: "memory");
    __builtin_amdgcn_sched_barrier(0);
    __builtin_amdgcn_s_barrier();
    if (t + 2 < DFF / 64) {
      const int nb = (t + 2) % 3, k2 = (t + 2) * 64;
      #pragma unroll
      for (int q = 0; q < 2; ++q) {
        dma16(ga[q] + k2, lA[nb][q]);
        dma16(gb[q] + k2, lB[nb][q]);
      }
    }
    const int bo = (t % 3) * 8192;
    #pragma unroll
    for (int ks = 0; ks < 2; ++ks) {
      const int ch = ks * 4 + qd;
      bf16x8 a0 = *(const bf16x8*)(sa + bo + LDSOFF(wm      + lr, ch));
      bf16x8 a1 = *(const bf16x8*)(sa + bo + LDSOFF(wm + 16 + lr, ch));
      bf16x8 b0 = *(const bf16x8*)(sb + bo + LDSOFF(wn      + lr, ch));
      bf16x8 b1 = *(const bf16x8*)(sb + bo + LDSOFF(wn + 16 + lr, ch));
      __builtin_amdgcn_s_setprio(1);
      acc[0][0] = MFMA(a0, b0, acc[0][0]);
      acc[0][1] = MFMA(a0, b1, acc[0][1]);
      acc[1][0] = MFMA(a1, b0, acc[1][0]);
      acc[1][1] = MFMA(a1, b1, acc[1][1]);
      __builtin_amdgcn_s_setprio(0);
    }
  }

  #pragma unroll
  for (int sm = 0; sm < 2; ++sm)
    #pragma unroll
    for (int sn = 0; sn < 2; ++sn) {
      const int col = n0 + wn + sn * 16 + lr;
      #pragma unroll
      for (int r = 0; r < 4; ++r) {
        const int ent = mt * 64 + wm + sm * 16 + qd * 4 + r;
        if (ent < cnt) {
          float v = acc[sm][sn][r];
          if (z == 0) {
            atomicAdd(out + (size_t)ent * DM + col, v);
          } else {
            const int   tok = list[(z - 1) * T_TOK + ent];
            const float g   = wgt [(z - 1) * T_TOK + ent];
            atomicAdd(out + (size_t)tok * DM + col, g * v);
          }
        }
      }
    }
}

// ---------------------------------------------------------------------------
extern "C" void kernel_launch(void* const* d_in, const int* in_sizes, int n_in,
                              void* d_out, int out_size, void* d_ws, size_t ws_size,
                              hipStream_t stream) {
  const float* x    = (const float*)d_in[0];
  const float* gw   = (const float*)d_in[1];
  const float* bias = (const float*)d_in[2];
  const float* sgu  = (const float*)d_in[3];
  const float* sdn  = (const float*)d_in[4];
  const float* egu  = (const float*)d_in[5];
  const float* edn  = (const float*)d_in[6];
  float* out = (float*)d_out;

  // workspace layout (bytes)
  char* ws = (char*)d_ws;
  int*            counts = (int*)(ws + 0);        // 16 ints
  int*            list   = (int*)(ws + 64);       // 16*2048 ints
  float*          wgt    = (float*)(ws + 131136); // 16*2048 floats
  unsigned short* Hall   = (unsigned short*)(ws + 262208); // 8192*512 bf16
  unsigned short* xb     = (unsigned short*)(ws + 8650816);
  unsigned short* sgub   = (unsigned short*)(ws + 10747968);
  unsigned short* sdnb   = (unsigned short*)(ws + 11796544);
  unsigned short* egub   = (unsigned short*)(ws + 12320832);
  unsigned short* ednb   = (unsigned short*)(ws + 29098048);
  const size_t need = 37486656;
  if (ws_size < need) return;

  hipMemsetAsync(counts, 0, 64, stream);
  prep_kernel<<<512 + 7040, 256, 0, stream>>>(
      x, gw, bias, counts, list, wgt, sgu, sdn, egu, edn,
      xb, sgub, sdnb, egub, ednb, out);
  gemm1_fused<<<dim3(8, 32, NE + 1), 256, 0, stream>>>(xb, sgub, egub, Hall, counts, list);
  gemm2_fused<<<dim3(8, 32, NE + 1), 256, 0, stream>>>(Hall, sdnb, ednb, out, counts, list, wgt);
}